// Round 8
// baseline (658.367 us; speedup 1.0000x reference)
//
#include <hip/hip_runtime.h>
#include <stdint.h>

#define DIM_C   2048
#define INNER_C 8192
#define ROWS    8192      // B*L = 4*2048
#define BM 128
#define BN 128
#define BK 64

using bf16x8  = __attribute__((ext_vector_type(8))) __bf16;
using f32x16  = __attribute__((ext_vector_type(16))) float;
using u16x8   = __attribute__((ext_vector_type(8))) unsigned short;

__device__ __forceinline__ unsigned short f2bf(float f) {
  union { float f; unsigned int u; } v; v.f = f;
  unsigned int u = v.u;
  return (unsigned short)((u + 0x7FFFu + ((u >> 16) & 1u)) >> 16);  // RTNE
}

__device__ __forceinline__ void gld_lds16(const void* g, void* l) {
  __builtin_amdgcn_global_load_lds(
      (__attribute__((address_space(1))) void*)(g),
      (__attribute__((address_space(3))) void*)(l), 16, 0, 0);
}

// --- softmax + per-batch truncation width --------------------------------
__global__ void prep_kernel(const float* __restrict__ logits,
                            float* __restrict__ p_out,
                            int* __restrict__ kb) {
  const int b = threadIdx.x;
  if (b < 4) {
    float x0 = logits[b * 4 + 0], x1 = logits[b * 4 + 1];
    float x2 = logits[b * 4 + 2], x3 = logits[b * 4 + 3];
    float m = fmaxf(fmaxf(x0, x1), fmaxf(x2, x3));
    float e0 = __expf(x0 - m), e1 = __expf(x1 - m);
    float e2 = __expf(x2 - m), e3 = __expf(x3 - m);
    float inv = 1.f / (e0 + e1 + e2 + e3);
    p_out[b * 4 + 0] = e0 * inv;
    p_out[b * 4 + 1] = e1 * inv;
    p_out[b * 4 + 2] = e2 * inv;
    p_out[b * 4 + 3] = e3 * inv;
    int idx = 0; float best = x0;                 // first-max, like jnp.argmax
    if (x1 > best) { best = x1; idx = 1; }
    if (x2 > best) { best = x2; idx = 2; }
    if (x3 > best) { best = x3; idx = 3; }
    kb[b] = (idx + 1) * (INNER_C / 4);
  }
}

// --- fp32 -> bf16 bulk convert (8 elems/thread, 16B stores) --------------
__global__ void cvt_kernel(const float* __restrict__ in,
                           unsigned short* __restrict__ out, int n8) {
  int i = blockIdx.x * blockDim.x + threadIdx.x;
  if (i >= n8) return;
  const float4* p = reinterpret_cast<const float4*>(in) + (size_t)i * 2;
  float4 a = p[0], b = p[1];
  u16x8 r;
  r[0] = f2bf(a.x); r[1] = f2bf(a.y); r[2] = f2bf(a.z); r[3] = f2bf(a.w);
  r[4] = f2bf(b.x); r[5] = f2bf(b.y); r[6] = f2bf(b.z); r[7] = f2bf(b.w);
  *(reinterpret_cast<u16x8*>(out) + i) = r;
}

// --- NT bf16 GEMM, m97 2-barrier structure + 32x32x16 MFMA + swizzle -----
// 128x128 tile, BK=64, 4 waves (2x2, 64x64/wave), LDS 32 KiB single-buf.
// LDS [128 rows][8 slots x 16B], slot XOR-swizzle: LDS[r][s] holds global
// slot s ^ (r&7) (both-sides, rule 21: pre-swizzled gld_lds source + XOR'd
// ds_read slot). Frag read: 8-lane groups cover all 32 banks once ->
// conflict-free (R4-verified family, counter 0).
// MFMA v_mfma_f32_32x32x16_bf16: A row=lane&31, k=(lane>>5)*8+e;
// C/D col=lane&31, row=(reg&3)+8*(reg>>2)+4*(lane>>5)  [m74/m101].
// MODE 0: C = gelu(A*B^T + bias) -> bf16 H, skip col tiles >= kb[batch]
// MODE 1: C = A*B^T + bias -> f32 out, K-loop truncated to kb[batch]
template <int MODE>
__global__ __launch_bounds__(256, 4) void gemm_bt(
    const unsigned short* __restrict__ A,
    const unsigned short* __restrict__ Bp,
    const float* __restrict__ bias,
    void* __restrict__ Cp,
    const int* __restrict__ kb_arr) {
  constexpr int KDIM = (MODE == 0) ? DIM_C : INNER_C;   // A/B row stride
  constexpr int NTN  = (MODE == 0) ? (INNER_C / BN) : (DIM_C / BN);
  __shared__ __align__(16) unsigned short As[BM * BK];
  __shared__ __align__(16) unsigned short Bs[BN * BK];

  // T1: bijective XCD swizzle (nwg % 8 == 0 for both grids)
  const int nwg = gridDim.x;
  const int bid = blockIdx.x;
  const int swz = (bid & 7) * (nwg >> 3) + (bid >> 3);
  const int nt = swz % NTN;
  const int mt = swz / NTN;
  const size_t row0 = (size_t)mt * BM;
  const size_t col0 = (size_t)nt * BN;
  const int batch = (int)(row0 >> 11);                  // 2048 rows / batch
  const int kbv = kb_arr[batch];
  if (MODE == 0 && (int)col0 >= kbv) return;            // masked cols: skip
  const int kTiles = (MODE == 0) ? (DIM_C / BK) : (kbv / BK);

  const int tid  = threadIdx.x;
  const int wave = tid >> 6;
  const int lane = tid & 63;
  const int wr0 = (wave >> 1) * 64;          // 2x2 wave grid, 64x64 per wave
  const int wc0 = (wave & 1) * 64;
  const int l31 = lane & 31, l5 = lane >> 5, l7 = lane & 7;

  // staging: per gld_lds, 8 rows x 128B; lane -> row lane>>3, LDS slot
  // lane&7; global slot pre-swizzled = (lane&7) ^ (row&7)
  const int sRow  = lane >> 3;
  const int sSlot = ((lane & 7) ^ (sRow & 7)) * 8;

  f32x16 acc[2][2];
#pragma unroll
  for (int m = 0; m < 2; ++m)
#pragma unroll
    for (int n = 0; n < 2; ++n)
#pragma unroll
      for (int r = 0; r < 16; ++r) acc[m][n][r] = 0.f;

  for (int kt = 0; kt < kTiles; ++kt) {
    __syncthreads();                         // protect LDS from overwrite
    const size_t kOff = (size_t)kt * BK + sSlot;
#pragma unroll
    for (int i = 0; i < 4; ++i) {
      const int q = wave * 4 + i;            // 16 x 1KB chunks per matrix
      const int r = q * 8 + sRow;
      gld_lds16(&A[(row0 + r) * KDIM + kOff], &As[q * 512]);
      gld_lds16(&Bp[(col0 + r) * KDIM + kOff], &Bs[q * 512]);
    }
    __syncthreads();                         // drains vmcnt before barrier
#pragma unroll
    for (int ks = 0; ks < 4; ++ks) {         // 4 k-steps of 16
      const int slot = ((ks * 2 + l5) ^ l7) * 8;
      bf16x8 a0 = *reinterpret_cast<const bf16x8*>(
          &As[(wr0 + l31) * BK + slot]);
      bf16x8 a1 = *reinterpret_cast<const bf16x8*>(
          &As[(wr0 + 32 + l31) * BK + slot]);
      bf16x8 b0 = *reinterpret_cast<const bf16x8*>(
          &Bs[(wc0 + l31) * BK + slot]);
      bf16x8 b1 = *reinterpret_cast<const bf16x8*>(
          &Bs[(wc0 + 32 + l31) * BK + slot]);
      acc[0][0] = __builtin_amdgcn_mfma_f32_32x32x16_bf16(a0, b0, acc[0][0], 0, 0, 0);
      acc[0][1] = __builtin_amdgcn_mfma_f32_32x32x16_bf16(a0, b1, acc[0][1], 0, 0, 0);
      acc[1][0] = __builtin_amdgcn_mfma_f32_32x32x16_bf16(a1, b0, acc[1][0], 0, 0, 0);
      acc[1][1] = __builtin_amdgcn_mfma_f32_32x32x16_bf16(a1, b1, acc[1][1], 0, 0, 0);
    }
  }

  // epilogue: C/D col = lane&31, row = (reg&3) + 8*(reg>>2) + 4*(lane>>5)
#pragma unroll
  for (int m = 0; m < 2; ++m) {
#pragma unroll
    for (int n = 0; n < 2; ++n) {
      const size_t c = col0 + wc0 + n * 32 + l31;
      const float bv = bias[c];
#pragma unroll
      for (int r = 0; r < 16; ++r) {
        const size_t rr =
            row0 + wr0 + m * 32 + (r & 3) + 8 * (r >> 2) + 4 * l5;
        float x = acc[m][n][r] + bv;
        if (MODE == 0) {
          float g = x / (1.f + __expf(-1.702f * x));  // x*sigmoid(1.702x)
          ((unsigned short*)Cp)[rr * (size_t)INNER_C + c] = f2bf(g);
        } else {
          ((float*)Cp)[rr * (size_t)DIM_C + c] = x;
        }
      }
    }
  }
}

extern "C" void kernel_launch(void* const* d_in, const int* in_sizes, int n_in,
                              void* d_out, int out_size, void* d_ws,
                              size_t ws_size, hipStream_t stream) {
  const float* hidden = (const float*)d_in[0];  // [4,2048,2048]
  const float* logitw = (const float*)d_in[1];  // [4,4]
  const float* W1     = (const float*)d_in[2];  // [8192,2048]
  const float* b1     = (const float*)d_in[3];  // [8192]
  const float* W2     = (const float*)d_in[4];  // [2048,8192]
  const float* b2     = (const float*)d_in[5];  // [2048]
  float* out   = (float*)d_out;
  float* p_out = out + (size_t)ROWS * DIM_C;    // tuple tail: p_soft [4,4]

  char* ws = (char*)d_ws;
  int*            kb   = (int*)ws;                                    // 16 B
  unsigned short* Abf  = (unsigned short*)(ws + 256);                 // 32 MiB
  unsigned short* W1bf = (unsigned short*)(ws + 256 + 33554432);      // 32 MiB
  unsigned short* W2bf = (unsigned short*)(ws + 256 + 2 * 33554432);  // 32 MiB
  unsigned short* Hbf  = (unsigned short*)(ws + 256 + 3 * 33554432);  // 128 MiB

  prep_kernel<<<1, 64, 0, stream>>>(logitw, p_out, kb);

  const int n8 = 16777216 / 8;  // each of A/W1/W2 is 16.7M fp32
  cvt_kernel<<<n8 / 256, 256, 0, stream>>>(hidden, Abf, n8);
  cvt_kernel<<<n8 / 256, 256, 0, stream>>>(W1, W1bf, n8);
  cvt_kernel<<<n8 / 256, 256, 0, stream>>>(W2, W2bf, n8);

  gemm_bt<0><<<dim3((INNER_C / BN) * (ROWS / BM)), 256, 0, stream>>>(
      Abf, W1bf, b1, Hbf, kb);
  gemm_bt<1><<<dim3((DIM_C / BN) * (ROWS / BM)), 256, 0, stream>>>(
      Hbf, W2bf, b2, out, kb);
}

// Round 9
// 562.483 us; speedup vs baseline: 1.1705x; 1.1705x over previous
//
#include <hip/hip_runtime.h>
#include <stdint.h>

#define DIM_C   2048
#define INNER_C 8192
#define ROWS    8192      // B*L = 4*2048
#define BM 128
#define BN 128
#define BK 64

using bf16x8  = __attribute__((ext_vector_type(8))) __bf16;
using f32x16  = __attribute__((ext_vector_type(16))) float;
using u16x8   = __attribute__((ext_vector_type(8))) unsigned short;

__device__ __forceinline__ unsigned short f2bf(float f) {
  union { float f; unsigned int u; } v; v.f = f;
  unsigned int u = v.u;
  return (unsigned short)((u + 0x7FFFu + ((u >> 16) & 1u)) >> 16);  // RTNE
}

__device__ __forceinline__ void gld_lds16(const void* g, void* l) {
  __builtin_amdgcn_global_load_lds(
      (__attribute__((address_space(1))) void*)(g),
      (__attribute__((address_space(3))) void*)(l), 16, 0, 0);
}

// --- softmax + per-batch truncation width --------------------------------
__global__ void prep_kernel(const float* __restrict__ logits,
                            float* __restrict__ p_out,
                            int* __restrict__ kb) {
  const int b = threadIdx.x;
  if (b < 4) {
    float x0 = logits[b * 4 + 0], x1 = logits[b * 4 + 1];
    float x2 = logits[b * 4 + 2], x3 = logits[b * 4 + 3];
    float m = fmaxf(fmaxf(x0, x1), fmaxf(x2, x3));
    float e0 = __expf(x0 - m), e1 = __expf(x1 - m);
    float e2 = __expf(x2 - m), e3 = __expf(x3 - m);
    float inv = 1.f / (e0 + e1 + e2 + e3);
    p_out[b * 4 + 0] = e0 * inv;
    p_out[b * 4 + 1] = e1 * inv;
    p_out[b * 4 + 2] = e2 * inv;
    p_out[b * 4 + 3] = e3 * inv;
    int idx = 0; float best = x0;                 // first-max, like jnp.argmax
    if (x1 > best) { best = x1; idx = 1; }
    if (x2 > best) { best = x2; idx = 2; }
    if (x3 > best) { best = x3; idx = 3; }
    kb[b] = (idx + 1) * (INNER_C / 4);
  }
}

// --- fp32 -> bf16 bulk convert (8 elems/thread, 16B stores) --------------
__global__ void cvt_kernel(const float* __restrict__ in,
                           unsigned short* __restrict__ out, int n8) {
  int i = blockIdx.x * blockDim.x + threadIdx.x;
  if (i >= n8) return;
  const float4* p = reinterpret_cast<const float4*>(in) + (size_t)i * 2;
  float4 a = p[0], b = p[1];
  u16x8 r;
  r[0] = f2bf(a.x); r[1] = f2bf(a.y); r[2] = f2bf(a.z); r[3] = f2bf(a.w);
  r[4] = f2bf(b.x); r[5] = f2bf(b.y); r[6] = f2bf(b.z); r[7] = f2bf(b.w);
  *(reinterpret_cast<u16x8*>(out) + i) = r;
}

// --- NT bf16 GEMM, m97 2-barrier structure + 32x32x16 MFMA + swizzle -----
// 128x128 tile, BK=64, 4 waves (2x2, 64x64/wave), LDS 32 KiB single-buf.
// Grid: R0's plain 2D (x = col tile fastest, NO XCD swizzle) — hardware
// round-robin gives each XCD ~1/8 of the col tiles -> B panel fits its L2
// (R8's chunked swizzle gave every XCD ALL col tiles: FETCH 296->721 MB).
// LDS [128 rows][8 slots x 16B], slot XOR-swizzle: LDS[r][s] holds global
// slot s ^ (r&7) (both-sides, rule 21: pre-swizzled gld_lds source + XOR'd
// ds_read slot). Frag reads are bank-uniform (R8: conflicts 8.2e7->2.7e7).
// MFMA v_mfma_f32_32x32x16_bf16: A row=lane&31, k=(lane>>5)*8+e;
// C/D col=lane&31, row=(reg&3)+8*(reg>>2)+4*(lane>>5)  [m74/m101;
// numerics verified R8: absmax 0.0039].
// MODE 0: C = gelu(A*B^T + bias) -> bf16 H, skip col tiles >= kb[batch]
// MODE 1: C = A*B^T + bias -> f32 out, K-loop truncated to kb[batch]
template <int MODE>
__global__ __launch_bounds__(256, 4) void gemm_bt(
    const unsigned short* __restrict__ A,
    const unsigned short* __restrict__ Bp,
    const float* __restrict__ bias,
    void* __restrict__ Cp,
    const int* __restrict__ kb_arr) {
  constexpr int KDIM = (MODE == 0) ? DIM_C : INNER_C;   // A/B row stride
  __shared__ __align__(16) unsigned short As[BM * BK];
  __shared__ __align__(16) unsigned short Bs[BN * BK];

  const int nt = blockIdx.x;
  const int mt = blockIdx.y;
  const size_t row0 = (size_t)mt * BM;
  const size_t col0 = (size_t)nt * BN;
  const int batch = (int)(row0 >> 11);                  // 2048 rows / batch
  const int kbv = kb_arr[batch];
  if (MODE == 0 && (int)col0 >= kbv) return;            // masked cols: skip
  const int kTiles = (MODE == 0) ? (DIM_C / BK) : (kbv / BK);

  const int tid  = threadIdx.x;
  const int wave = tid >> 6;
  const int lane = tid & 63;
  const int wr0 = (wave >> 1) * 64;          // 2x2 wave grid, 64x64 per wave
  const int wc0 = (wave & 1) * 64;
  const int l31 = lane & 31, l5 = lane >> 5, l7 = lane & 7;

  // staging: per gld_lds, 8 rows x 128B; lane -> row lane>>3, LDS slot
  // lane&7; global slot pre-swizzled = (lane&7) ^ (row&7)
  const int sRow  = lane >> 3;
  const int sSlot = ((lane & 7) ^ (sRow & 7)) * 8;

  f32x16 acc[2][2];
#pragma unroll
  for (int m = 0; m < 2; ++m)
#pragma unroll
    for (int n = 0; n < 2; ++n)
#pragma unroll
      for (int r = 0; r < 16; ++r) acc[m][n][r] = 0.f;

  for (int kt = 0; kt < kTiles; ++kt) {
    __syncthreads();                         // protect LDS from overwrite
    const size_t kOff = (size_t)kt * BK + sSlot;
#pragma unroll
    for (int i = 0; i < 4; ++i) {
      const int q = wave * 4 + i;            // 16 x 1KB chunks per matrix
      const int r = q * 8 + sRow;
      gld_lds16(&A[(row0 + r) * KDIM + kOff], &As[q * 512]);
      gld_lds16(&Bp[(col0 + r) * KDIM + kOff], &Bs[q * 512]);
    }
    __syncthreads();                         // drains vmcnt before barrier
#pragma unroll
    for (int ks = 0; ks < 4; ++ks) {         // 4 k-steps of 16
      const int slot = ((ks * 2 + l5) ^ l7) * 8;
      bf16x8 a0 = *reinterpret_cast<const bf16x8*>(
          &As[(wr0 + l31) * BK + slot]);
      bf16x8 a1 = *reinterpret_cast<const bf16x8*>(
          &As[(wr0 + 32 + l31) * BK + slot]);
      bf16x8 b0 = *reinterpret_cast<const bf16x8*>(
          &Bs[(wc0 + l31) * BK + slot]);
      bf16x8 b1 = *reinterpret_cast<const bf16x8*>(
          &Bs[(wc0 + 32 + l31) * BK + slot]);
      acc[0][0] = __builtin_amdgcn_mfma_f32_32x32x16_bf16(a0, b0, acc[0][0], 0, 0, 0);
      acc[0][1] = __builtin_amdgcn_mfma_f32_32x32x16_bf16(a0, b1, acc[0][1], 0, 0, 0);
      acc[1][0] = __builtin_amdgcn_mfma_f32_32x32x16_bf16(a1, b0, acc[1][0], 0, 0, 0);
      acc[1][1] = __builtin_amdgcn_mfma_f32_32x32x16_bf16(a1, b1, acc[1][1], 0, 0, 0);
    }
  }

  // epilogue: C/D col = lane&31, row = (reg&3) + 8*(reg>>2) + 4*(lane>>5)
#pragma unroll
  for (int m = 0; m < 2; ++m) {
#pragma unroll
    for (int n = 0; n < 2; ++n) {
      const size_t c = col0 + wc0 + n * 32 + l31;
      const float bv = bias[c];
#pragma unroll
      for (int r = 0; r < 16; ++r) {
        const size_t rr =
            row0 + wr0 + m * 32 + (r & 3) + 8 * (r >> 2) + 4 * l5;
        float x = acc[m][n][r] + bv;
        if (MODE == 0) {
          float g = x / (1.f + __expf(-1.702f * x));  // x*sigmoid(1.702x)
          ((unsigned short*)Cp)[rr * (size_t)INNER_C + c] = f2bf(g);
        } else {
          ((float*)Cp)[rr * (size_t)DIM_C + c] = x;
        }
      }
    }
  }
}

extern "C" void kernel_launch(void* const* d_in, const int* in_sizes, int n_in,
                              void* d_out, int out_size, void* d_ws,
                              size_t ws_size, hipStream_t stream) {
  const float* hidden = (const float*)d_in[0];  // [4,2048,2048]
  const float* logitw = (const float*)d_in[1];  // [4,4]
  const float* W1     = (const float*)d_in[2];  // [8192,2048]
  const float* b1     = (const float*)d_in[3];  // [8192]
  const float* W2     = (const float*)d_in[4];  // [2048,8192]
  const float* b2     = (const float*)d_in[5];  // [2048]
  float* out   = (float*)d_out;
  float* p_out = out + (size_t)ROWS * DIM_C;    // tuple tail: p_soft [4,4]

  char* ws = (char*)d_ws;
  int*            kb   = (int*)ws;                                    // 16 B
  unsigned short* Abf  = (unsigned short*)(ws + 256);                 // 32 MiB
  unsigned short* W1bf = (unsigned short*)(ws + 256 + 33554432);      // 32 MiB
  unsigned short* W2bf = (unsigned short*)(ws + 256 + 2 * 33554432);  // 32 MiB
  unsigned short* Hbf  = (unsigned short*)(ws + 256 + 3 * 33554432);  // 128 MiB

  prep_kernel<<<1, 64, 0, stream>>>(logitw, p_out, kb);

  const int n8 = 16777216 / 8;  // each of A/W1/W2 is 16.7M fp32
  cvt_kernel<<<n8 / 256, 256, 0, stream>>>(hidden, Abf, n8);
  cvt_kernel<<<n8 / 256, 256, 0, stream>>>(W1, W1bf, n8);
  cvt_kernel<<<n8 / 256, 256, 0, stream>>>(W2, W2bf, n8);

  gemm_bt<0><<<dim3(INNER_C / BN, ROWS / BM), 256, 0, stream>>>(
      Abf, W1bf, b1, Hbf, kb);
  gemm_bt<1><<<dim3(DIM_C / BN, ROWS / BM), 256, 0, stream>>>(
      Hbf, W2bf, b2, out, kb);
}